// Round 3
// baseline (1116.290 us; speedup 1.0000x reference)
//
#include <hip/hip_runtime.h>
#include <math.h>

#define NWF    307
#define NWTOT  614
#define MROWS  39296   // NWTOT * 64

typedef float f32x4 __attribute__((ext_vector_type(4)));
typedef short s16x8 __attribute__((ext_vector_type(8)));

__device__ __forceinline__ short f2bf(float f) {
  unsigned int u = __builtin_bit_cast(unsigned int, f);
  u += 0x7fffu + ((u >> 16) & 1u);
  return (short)(u >> 16);
}

__device__ __forceinline__ f32x4 mfma16(s16x8 a, s16x8 b, f32x4 c) {
  return __builtin_amdgcn_mfma_f32_16x16x32_bf16(a, b, c, 0, 0, 0);
}

__device__ __forceinline__ float max3f(float a, float b, float c) {
  float d;
  asm("v_max3_f32 %0, %1, %2, %3" : "=v"(d) : "v"(a), "v"(b), "v"(c));
  return d;
}

// ---------------- window scores: mean of 64 uncertainty values ----------------
__global__ __launch_bounds__(64) void score_k(const float* __restrict__ unc,
                                              float* __restrict__ scores) {
  int blk = blockIdx.x;              // 0..2047 = b*1024 + win
  int b = blk >> 10, t = blk & 1023;
  int ty = t >> 5, tx = t & 31;
  int lane = threadIdx.x;
  float v = unc[(size_t)b * 65536 + (size_t)(ty * 8 + (lane >> 3)) * 256 + tx * 8 + (lane & 7)];
  for (int m = 32; m; m >>= 1) v += __shfl_xor(v, m);
  if (lane == 0) scores[blk] = v * (1.0f / 64.0f);
}

// ---------------- exact top-k via rank counting (per batch) ----------------
__global__ __launch_bounds__(1024) void topk_k(const float* __restrict__ scores,
                                               int* __restrict__ selidx) {
  __shared__ float sc[1024];
  int b = blockIdx.x, t = threadIdx.x;
  float s = scores[b * 1024 + t];
  sc[t] = s;
  __syncthreads();
  int rank = 0;
  for (int j = 0; j < 1024; ++j) {
    float o = sc[j];
    rank += (o > s) || (o == s && j < t);
  }
  if (rank < NWF) selidx[b * NWF + rank] = t;
}

// ---------------- gather selected windows: wf[slot][tok][c] ----------------
__global__ __launch_bounds__(256) void gather_k(const float* __restrict__ fm,
                                                const int* __restrict__ selidx,
                                                float* __restrict__ wf) {
  __shared__ float tile[64][33];
  int slot = blockIdx.x;
  int b = slot >= NWF;
  int w = selidx[slot];
  int y0 = (w >> 5) * 8, x0 = (w & 31) * 8;
  int tid = threadIdx.x;
  int j = tid & 7, i = (tid >> 3) & 7, c4 = tid >> 6;   // read mapping
  int cc2 = tid & 31, t4 = tid >> 5;                    // write mapping
  for (int c0 = 0; c0 < 256; c0 += 32) {
    for (int cs = 0; cs < 8; ++cs) {
      int c = c0 + cs * 4 + c4;
      tile[i * 8 + j][cs * 4 + c4] =
          fm[((size_t)(b * 256 + c) * 256 + y0 + i) * 256 + x0 + j];
    }
    __syncthreads();
    for (int ts = 0; ts < 8; ++ts) {
      int tok = ts * 8 + t4;
      wf[(size_t)(slot * 64 + tok) * 256 + c0 + cc2] = tile[tok][cc2];
    }
    __syncthreads();
  }
}

// ------- fused: out=fm copy + depthwise 8x8/8 conv + LayerNorm + exact GELU -------
// grid: 512 blocks = b(2) * ty(32) * txg(8); thread = channel; 4 tokens per block
__global__ __launch_bounds__(256) void convcopy_k(const float* __restrict__ fm,
                                                  const float* __restrict__ srw,
                                                  const float* __restrict__ srb,
                                                  const float* __restrict__ lng,
                                                  const float* __restrict__ lnb,
                                                  float* __restrict__ g,
                                                  float* __restrict__ out) {
  int blk = blockIdx.x;
  int b = blk >> 8, rr = blk & 255, ty = rr >> 3, txg = rr & 7;
  int c = threadIdx.x;
  int lane = c & 63, wv = c >> 6;
  size_t base = ((size_t)(b * 256 + c) * 256 + ty * 8) * 256 + txg * 32;
  const float* fp = fm + base;
  float* op = out + base;
  const float* wp = srw + c * 64;
  float acc[4] = {0.f, 0.f, 0.f, 0.f};
#pragma unroll
  for (int i = 0; i < 8; ++i) {
    f32x4 r[8];
#pragma unroll
    for (int u = 0; u < 8; ++u) r[u] = *(const f32x4*)(fp + (size_t)i * 256 + u * 4);
#pragma unroll
    for (int u = 0; u < 8; ++u) *(f32x4*)(op + (size_t)i * 256 + u * 4) = r[u];
    f32x4 w0 = *(const f32x4*)(wp + i * 8);
    f32x4 w1 = *(const f32x4*)(wp + i * 8 + 4);
#pragma unroll
    for (int t = 0; t < 4; ++t) {
      f32x4 ra = r[2 * t], rb = r[2 * t + 1];
      acc[t] += ra[0] * w0[0] + ra[1] * w0[1] + ra[2] * w0[2] + ra[3] * w0[3]
              + rb[0] * w1[0] + rb[1] * w1[1] + rb[2] * w1[2] + rb[3] * w1[3];
    }
  }
  float sb = srb[c];
#pragma unroll
  for (int t = 0; t < 4; ++t) acc[t] += sb;
  __shared__ float red[4][8];
#pragma unroll
  for (int t = 0; t < 4; ++t) {
    float s = acc[t], q = acc[t] * acc[t];
    for (int m = 32; m; m >>= 1) { s += __shfl_xor(s, m); q += __shfl_xor(q, m); }
    if (lane == 0) { red[t][wv] = s; red[t][4 + wv] = q; }
  }
  __syncthreads();
  float gc = lng[c], bc = lnb[c];
#pragma unroll
  for (int t = 0; t < 4; ++t) {
    float sum = red[t][0] + red[t][1] + red[t][2] + red[t][3];
    float sq  = red[t][4] + red[t][5] + red[t][6] + red[t][7];
    float mu  = sum * (1.f / 256.f);
    float var = sq * (1.f / 256.f) - mu * mu;
    float xn = (acc[t] - mu) * rsqrtf(var + 1e-5f);
    float y = xn * gc + bc;
    float ge = 0.5f * y * (1.f + erff(y * 0.70710678118654752f));
    g[(size_t)(b * 1024 + ty * 32 + txg * 4 + t) * 256 + c] = ge;
  }
}

// ---------------- weight transpose + bf16 cast: Wt[n][k] = bf16(W[k][n]) ----------------
__global__ __launch_bounds__(256) void wtrans_k(const float* __restrict__ W,
                                                short* __restrict__ Wt, int N) {
  int n = blockIdx.x, k = threadIdx.x;
  Wt[(size_t)n * 256 + k] = f2bf(W[(size_t)k * N + n]);
}

// ---------------- GEMM: Y = X[M,256] @ W[256,N]; wave = 16 rows x 128 cols ----------------
// grid: (M/64, N/128). EPI 0: bf16 [row][col] * scale. EPI 1: col<256 -> kbuf bf16; else vT.
// EPI 2: fp32 [row][col] = acc + bias[col].
template <int EPI>
__global__ __launch_bounds__(256) void gemm_k(const float* __restrict__ X,
                                              const short* __restrict__ Wt,
                                              const float* __restrict__ bias,
                                              short* __restrict__ outb,
                                              short* __restrict__ outvT,
                                              float* __restrict__ outf,
                                              int kvshift, float scale) {
  const int lane = threadIdx.x & 63;
  const int wv = threadIdx.x >> 6;
  const int l16 = lane & 15, quad = lane >> 4;
  const int row0 = blockIdx.x * 64 + wv * 16;
  const int col0 = blockIdx.y * 128;
  f32x4 acc[8];
#pragma unroll
  for (int i = 0; i < 8; ++i) { acc[i][0] = 0.f; acc[i][1] = 0.f; acc[i][2] = 0.f; acc[i][3] = 0.f; }
  const float* xrow = X + (size_t)(row0 + l16) * 256 + quad * 8;
  const short* wbase = Wt + (size_t)(col0 + l16) * 256 + quad * 8;
#pragma unroll
  for (int ks = 0; ks < 8; ++ks) {
    f32x4 xa = *(const f32x4*)(xrow + ks * 32);
    f32x4 xb = *(const f32x4*)(xrow + ks * 32 + 4);
    s16x8 a;
    a[0] = f2bf(xa[0]); a[1] = f2bf(xa[1]); a[2] = f2bf(xa[2]); a[3] = f2bf(xa[3]);
    a[4] = f2bf(xb[0]); a[5] = f2bf(xb[1]); a[6] = f2bf(xb[2]); a[7] = f2bf(xb[3]);
#pragma unroll
    for (int nt = 0; nt < 8; ++nt) {
      s16x8 b = *(const s16x8*)(wbase + (size_t)nt * 16 * 256 + ks * 32);
      acc[nt] = mfma16(a, b, acc[nt]);
    }
  }
#pragma unroll
  for (int nt = 0; nt < 8; ++nt) {
#pragma unroll
    for (int r = 0; r < 4; ++r) {
      int col = col0 + nt * 16 + l16;
      int row = row0 + quad * 4 + r;
      float v = acc[nt][r];
      if (EPI == 0) {
        outb[(size_t)row * 256 + col] = f2bf(v * scale);
      } else if (EPI == 1) {
        if (col < 256) {
          outb[(size_t)row * 256 + col] = f2bf(v);
        } else {
          int c2 = col - 256, hh = c2 >> 6, ch = c2 & 63;
          int grp = row >> kvshift, tok = row & ((1 << kvshift) - 1);
          outvT[((size_t)((grp * 4 + hh) * 64 + ch) << kvshift) + tok] = f2bf(v);
        }
      } else {
        outf[(size_t)row * 256 + col] = v + bias[col];
      }
    }
  }
}

// ---------------- flash attention: wave = (window, head, 16-row q-tile) ----------------
// Swapped-operand QK^T (S' = mfma(K, Q)): softmax state per-lane (qrow = l16).
// Q pre-scaled by 0.125*log2e in the q-GEMM, so S is directly in log2 units.
// T13 defer-rescale: O-rescale only when row-max grows > 8 (log2 units).
// P transpose: cvt_pk -> XOR-swizzled per-wave LDS (conflict-free b64/b128), no barriers.
// K double-buffered in regs; V issued at tile start. sched_barrier(0) after each
// load-issue cluster pins the issue point (round-1 failure: compiler sank all
// prefetch loads to their uses -> VGPR=96, full L2 latency exposed twice/tile).
__global__ __launch_bounds__(256, 2) void attn_k(const short* __restrict__ qbuf,
                                                 const short* __restrict__ kbuf,
                                                 const short* __restrict__ vT,
                                                 float* __restrict__ wf, int kvlen) {
  __shared__ short Plds[4][16 * 64];            // per-wave 16 rows x 128B, XOR-swizzled
  const int w = threadIdx.x >> 6, lane = threadIdx.x & 63;
  const int l16 = lane & 15, quad = lane >> 4;
  const int gid = blockIdx.x * 4 + w;
  const int qt = gid & 3, h = (gid >> 2) & 3, win = gid >> 4;
  const int qrow0 = win * 64 + qt * 16;
  const int grp = (kvlen == 64) ? win : (win >= NWF ? 1 : 0);

  s16x8 aq[2];
#pragma unroll
  for (int ks = 0; ks < 2; ++ks)
    aq[ks] = *(const s16x8*)(qbuf + (size_t)(qrow0 + l16) * 256 + h * 64 + ks * 32 + quad * 8);

  f32x4 O[4];
#pragma unroll
  for (int nt = 0; nt < 4; ++nt)
#pragma unroll
    for (int r = 0; r < 4; ++r) O[nt][r] = 0.f;
  float m2 = -1e30f, li = 0.f;                  // per-lane; li = this quad's partial sum

  const short* kp = kbuf + ((size_t)grp * kvlen + l16) * 256 + h * 64 + quad * 8;
  const short* vp = vT + ((size_t)((grp * 4 + h) * 64) + l16) * kvlen + quad * 8;
  char* Pw = (char*)&Plds[w][0] + l16 * 128;
  const int sw = (l16 & 7) << 4;
  const int ntile = kvlen >> 6;

  auto loadK = [&](s16x8 (&kr)[2][4], const short* p) {
#pragma unroll
    for (int ks = 0; ks < 2; ++ks)
#pragma unroll
      for (int nt = 0; nt < 4; ++nt)
        kr[ks][nt] = *(const s16x8*)(p + nt * 4096 + ks * 32);
    __builtin_amdgcn_sched_barrier(0);          // pin load-issue point (no sinking)
  };

  auto tileStep = [&](const s16x8 (&kr)[2][4], const short* vq) {
    // issue V loads first; sched_barrier pins them so they fly under QK+softmax
    s16x8 vr[2][4];
#pragma unroll
    for (int ks2 = 0; ks2 < 2; ++ks2)
#pragma unroll
      for (int nt = 0; nt < 4; ++nt)
        vr[ks2][nt] = *(const s16x8*)(vq + (size_t)nt * 16 * kvlen + ks2 * 32);
    __builtin_amdgcn_sched_barrier(0);
    // S'[kpos][qrow]: lane l16 = qrow; kpos = nt*16 + quad*4 + r
    f32x4 S[4];
#pragma unroll
    for (int nt = 0; nt < 4; ++nt)
#pragma unroll
      for (int r = 0; r < 4; ++r) S[nt][r] = 0.f;
    __builtin_amdgcn_s_setprio(1);
#pragma unroll
    for (int ks = 0; ks < 2; ++ks)
#pragma unroll
      for (int nt = 0; nt < 4; ++nt)
        S[nt] = mfma16(kr[ks][nt], aq[ks], S[nt]);
    __builtin_amdgcn_s_setprio(0);
    // row max: max3 tree over the lane's 16 values + cross-quad
    float a0 = max3f(S[0][0], S[0][1], S[0][2]);
    float a1 = max3f(S[0][3], S[1][0], S[1][1]);
    float a2 = max3f(S[1][2], S[1][3], S[2][0]);
    float a3 = max3f(S[2][1], S[2][2], S[2][3]);
    float a4 = max3f(S[3][0], S[3][1], S[3][2]);
    float b0 = max3f(a0, a1, S[3][3]);
    float b1 = max3f(a2, a3, a4);
    float mx = fmaxf(b0, b1);
    mx = fmaxf(mx, __shfl_xor(mx, 16));
    mx = fmaxf(mx, __shfl_xor(mx, 32));
    if (__any(mx > m2 + 8.0f)) {                 // T13: rescale only on real max growth
      float mn = fmaxf(m2, mx);
      float al = __builtin_amdgcn_exp2f(m2 - mn);
      m2 = mn;
      li *= al;
      float alr[4];
#pragma unroll
      for (int r = 0; r < 4; ++r) alr[r] = __shfl(al, quad * 4 + r);
#pragma unroll
      for (int nt = 0; nt < 4; ++nt)
#pragma unroll
        for (int r = 0; r < 4; ++r) O[nt][r] *= alr[r];
    }
    float rs = 0.f;
#pragma unroll
    for (int nt = 0; nt < 4; ++nt)
#pragma unroll
      for (int r = 0; r < 4; ++r) {
        float p = __builtin_amdgcn_exp2f(S[nt][r] - m2);
        S[nt][r] = p;
        rs += p;
      }
    li += rs;                                    // cross-quad sum deferred to epilogue
    // P -> bf16 packed -> swizzled per-wave LDS (conflict-free), no barrier
#pragma unroll
    for (int nt = 0; nt < 4; ++nt) {
      unsigned int w0, w1;
      asm("v_cvt_pk_bf16_f32 %0, %1, %2" : "=v"(w0) : "v"(S[nt][0]), "v"(S[nt][1]));
      asm("v_cvt_pk_bf16_f32 %0, %1, %2" : "=v"(w1) : "v"(S[nt][2]), "v"(S[nt][3]));
      uint2 pw; pw.x = w0; pw.y = w1;
      *(uint2*)(Pw + ((nt * 32 + quad * 8) ^ sw)) = pw;
    }
#pragma unroll
    for (int ks2 = 0; ks2 < 2; ++ks2) {
      s16x8 ap = *(const s16x8*)(Pw + ((ks2 * 64 + quad * 16) ^ sw));
      __builtin_amdgcn_s_setprio(1);
#pragma unroll
      for (int nt = 0; nt < 4; ++nt)
        O[nt] = mfma16(ap, vr[ks2][nt], O[nt]);
      __builtin_amdgcn_s_setprio(0);
    }
  };

  s16x8 ka[2][4], kb[2][4];
  loadK(ka, kp);
  for (int t = 0; t < ntile; t += 2) {
    if (t + 1 < ntile) loadK(kb, kp + 16384);
    tileStep(ka, vp);
    vp += 64;
    if (t + 1 < ntile) {
      if (t + 2 < ntile) loadK(ka, kp + 32768);
      tileStep(kb, vp);
      vp += 64;
    }
    kp += 32768;
  }

  li += __shfl_xor(li, 16);
  li += __shfl_xor(li, 32);
  float inv = 1.f / li;
  float invr[4];
#pragma unroll
  for (int r = 0; r < 4; ++r) invr[r] = __shfl(inv, quad * 4 + r);
#pragma unroll
  for (int nt = 0; nt < 4; ++nt)
#pragma unroll
    for (int r = 0; r < 4; ++r) {
      size_t oi = (size_t)(qrow0 + quad * 4 + r) * 256 + h * 64 + nt * 16 + l16;
      wf[oi] += O[nt][r] * invr[r];
    }
}

// ---------------- scatter-add projected windows into out (LDS transpose) ----------------
__global__ __launch_bounds__(256) void scatter_k(const float* __restrict__ proj,
                                                 const int* __restrict__ selidx,
                                                 float* __restrict__ out) {
  __shared__ float tile[64][33];
  int slot = blockIdx.x;
  int b = slot >= NWF;
  int w = selidx[slot];
  int y0 = (w >> 5) * 8, x0 = (w & 31) * 8;
  int tid = threadIdx.x;
  int cc2 = tid & 31, t4 = tid >> 5;                    // coalesced proj read
  int j = tid & 7, i = (tid >> 3) & 7, c4 = tid >> 6;   // out RMW mapping
  for (int c0 = 0; c0 < 256; c0 += 32) {
    for (int ts = 0; ts < 8; ++ts) {
      int tok = ts * 8 + t4;
      tile[tok][cc2] = proj[(size_t)(slot * 64 + tok) * 256 + c0 + cc2];
    }
    __syncthreads();
    for (int cs = 0; cs < 8; ++cs) {
      int c = c0 + cs * 4 + c4;
      size_t oidx = ((size_t)(b * 256 + c) * 256 + y0 + i) * 256 + x0 + j;
      out[oidx] += tile[i * 8 + j][cs * 4 + c4];
    }
    __syncthreads();
  }
}

extern "C" void kernel_launch(void* const* d_in, const int* in_sizes, int n_in,
                              void* d_out, int out_size, void* d_ws, size_t ws_size,
                              hipStream_t stream) {
  const float* fm    = (const float*)d_in[0];
  const float* unc   = (const float*)d_in[1];
  const float* srw   = (const float*)d_in[2];
  const float* srb   = (const float*)d_in[3];
  const float* lng   = (const float*)d_in[4];
  const float* lnb   = (const float*)d_in[5];
  const float* wq_l  = (const float*)d_in[6];
  const float* wkv_l = (const float*)d_in[7];
  const float* wq_g  = (const float*)d_in[8];
  const float* wkv_g = (const float*)d_in[9];
  const float* wpm   = (const float*)d_in[10];
  const float* bp    = (const float*)d_in[11];
  float* out = (float*)d_out;

  char* ws = (char*)d_ws;
  size_t off = 0;
  auto alloc = [&](size_t bytes) -> char* {
    char* p = ws + off;
    off += (bytes + 255) & ~(size_t)255;
    return p;
  };
  float* wf     = (float*)alloc((size_t)MROWS * 256 * 4);
  short* qbuf   = (short*)alloc((size_t)MROWS * 256 * 2);
  short* kbufl  = (short*)alloc((size_t)MROWS * 256 * 2);   // contiguous with qbuf
  short* vTl    = (short*)alloc((size_t)MROWS * 256 * 2);
  short* kbufg  = (short*)alloc((size_t)2048 * 256 * 2);
  short* vTg    = (short*)alloc((size_t)2048 * 256 * 2);
  float* g      = (float*)alloc((size_t)2048 * 256 * 4);
  float* scores = (float*)alloc(2048 * 4);
  int*   selidx = (int*)alloc(NWTOT * 4);
  short* wtql   = (short*)alloc(256 * 256 * 2);
  short* wtkvl  = (short*)alloc(512 * 256 * 2);
  short* wtqg   = (short*)alloc(256 * 256 * 2);
  short* wtkvg  = (short*)alloc(512 * 256 * 2);
  short* wtp    = (short*)alloc(256 * 256 * 2);
  float* proj   = (float*)qbuf;   // aliases qbuf+kbufl (both dead by projection time)

  const float C1 = 0.125f * 1.4426950408889634f;   // head-scale * log2(e)

  // weights -> bf16 transposed
  wtrans_k<<<256, 256, 0, stream>>>(wq_l, wtql, 256);
  wtrans_k<<<512, 256, 0, stream>>>(wkv_l, wtkvl, 512);
  wtrans_k<<<256, 256, 0, stream>>>(wq_g, wtqg, 256);
  wtrans_k<<<512, 256, 0, stream>>>(wkv_g, wtkvg, 512);
  wtrans_k<<<256, 256, 0, stream>>>(wpm, wtp, 256);

  // selection
  score_k<<<2048, 64, 0, stream>>>(unc, scores);
  topk_k<<<2, 1024, 0, stream>>>(scores, selidx);
  gather_k<<<NWTOT, 256, 0, stream>>>(fm, selidx, wf);

  // fused identity-copy + global branch (conv + LN + GELU)
  convcopy_k<<<512, 256, 0, stream>>>(fm, srw, srb, lng, lnb, g, out);

  // local window attention (q pre-scaled so S is in log2 units)
  gemm_k<0><<<dim3(NWTOT, 2), 256, 0, stream>>>(wf, wtql, nullptr, qbuf, nullptr, nullptr, 0, C1);
  gemm_k<1><<<dim3(NWTOT, 4), 256, 0, stream>>>(wf, wtkvl, nullptr, kbufl, vTl, nullptr, 6, 1.0f);
  attn_k<<<NWTOT * 4, 256, 0, stream>>>(qbuf, kbufl, vTl, wf, 64);

  // global cross attention
  gemm_k<0><<<dim3(NWTOT, 2), 256, 0, stream>>>(wf, wtqg, nullptr, qbuf, nullptr, nullptr, 0, C1);
  gemm_k<1><<<dim3(32, 4), 256, 0, stream>>>(g, wtkvg, nullptr, kbufg, vTg, nullptr, 10, 1.0f);
  attn_k<<<NWTOT * 4, 256, 0, stream>>>(qbuf, kbufg, vTg, wf, 1024);

  // projection + scatter-add
  gemm_k<2><<<dim3(NWTOT, 2), 256, 0, stream>>>(wf, wtp, bp, nullptr, nullptr, proj, 0, 1.0f);
  scatter_k<<<NWTOT, 256, 0, stream>>>(proj, selidx, out);
}

// Round 5
// 929.710 us; speedup vs baseline: 1.2007x; 1.2007x over previous
//
#include <hip/hip_runtime.h>
#include <math.h>

#define NWF    307
#define NWTOT  614
#define MROWS  39296   // NWTOT * 64

typedef float f32x4 __attribute__((ext_vector_type(4)));
typedef short s16x8 __attribute__((ext_vector_type(8)));

__device__ __forceinline__ short f2bf(float f) {
  unsigned int u = __builtin_bit_cast(unsigned int, f);
  u += 0x7fffu + ((u >> 16) & 1u);
  return (short)(u >> 16);
}

__device__ __forceinline__ unsigned int pk2bf(float lo, float hi) {
  return (unsigned int)(unsigned short)f2bf(lo) |
         ((unsigned int)(unsigned short)f2bf(hi) << 16);
}

__device__ __forceinline__ f32x4 mfma16(s16x8 a, s16x8 b, f32x4 c) {
  return __builtin_amdgcn_mfma_f32_16x16x32_bf16(a, b, c, 0, 0, 0);
}

// ---------------- window scores: mean of 64 uncertainty values ----------------
__global__ __launch_bounds__(64) void score_k(const float* __restrict__ unc,
                                              float* __restrict__ scores) {
  int blk = blockIdx.x;              // 0..2047 = b*1024 + win
  int b = blk >> 10, t = blk & 1023;
  int ty = t >> 5, tx = t & 31;
  int lane = threadIdx.x;
  float v = unc[(size_t)b * 65536 + (size_t)(ty * 8 + (lane >> 3)) * 256 + tx * 8 + (lane & 7)];
  for (int m = 32; m; m >>= 1) v += __shfl_xor(v, m);
  if (lane == 0) scores[blk] = v * (1.0f / 64.0f);
}

// ---------------- exact top-k via rank counting (per batch) ----------------
__global__ __launch_bounds__(1024) void topk_k(const float* __restrict__ scores,
                                               int* __restrict__ selidx) {
  __shared__ float sc[1024];
  int b = blockIdx.x, t = threadIdx.x;
  float s = scores[b * 1024 + t];
  sc[t] = s;
  __syncthreads();
  int rank = 0;
  for (int j = 0; j < 1024; ++j) {
    float o = sc[j];
    rank += (o > s) || (o == s && j < t);
  }
  if (rank < NWF) selidx[b * NWF + rank] = t;
}

// ---------------- gather selected windows: wf[slot][tok][c] ----------------
__global__ __launch_bounds__(256) void gather_k(const float* __restrict__ fm,
                                                const int* __restrict__ selidx,
                                                float* __restrict__ wf) {
  __shared__ float tile[64][33];
  int slot = blockIdx.x;
  int b = slot >= NWF;
  int w = selidx[slot];
  int y0 = (w >> 5) * 8, x0 = (w & 31) * 8;
  int tid = threadIdx.x;
  int j = tid & 7, i = (tid >> 3) & 7, c4 = tid >> 6;   // read mapping
  int cc2 = tid & 31, t4 = tid >> 5;                    // write mapping
  for (int c0 = 0; c0 < 256; c0 += 32) {
    for (int cs = 0; cs < 8; ++cs) {
      int c = c0 + cs * 4 + c4;
      tile[i * 8 + j][cs * 4 + c4] =
          fm[((size_t)(b * 256 + c) * 256 + y0 + i) * 256 + x0 + j];
    }
    __syncthreads();
    for (int ts = 0; ts < 8; ++ts) {
      int tok = ts * 8 + t4;
      wf[(size_t)(slot * 64 + tok) * 256 + c0 + cc2] = tile[tok][cc2];
    }
    __syncthreads();
  }
}

// ------- fused: out=fm copy + depthwise 8x8/8 conv + LayerNorm + exact GELU -------
// grid: 512 blocks = b(2) * ty(32) * txg(8); thread = channel; 4 tokens per block
__global__ __launch_bounds__(256) void convcopy_k(const float* __restrict__ fm,
                                                  const float* __restrict__ srw,
                                                  const float* __restrict__ srb,
                                                  const float* __restrict__ lng,
                                                  const float* __restrict__ lnb,
                                                  float* __restrict__ g,
                                                  float* __restrict__ out) {
  int blk = blockIdx.x;
  int b = blk >> 8, rr = blk & 255, ty = rr >> 3, txg = rr & 7;
  int c = threadIdx.x;
  int lane = c & 63, wv = c >> 6;
  size_t base = ((size_t)(b * 256 + c) * 256 + ty * 8) * 256 + txg * 32;
  const float* fp = fm + base;
  float* op = out + base;
  const float* wp = srw + c * 64;
  float acc[4] = {0.f, 0.f, 0.f, 0.f};
#pragma unroll
  for (int i = 0; i < 8; ++i) {
    f32x4 r[8];
#pragma unroll
    for (int u = 0; u < 8; ++u) r[u] = *(const f32x4*)(fp + (size_t)i * 256 + u * 4);
#pragma unroll
    for (int u = 0; u < 8; ++u) *(f32x4*)(op + (size_t)i * 256 + u * 4) = r[u];
    f32x4 w0 = *(const f32x4*)(wp + i * 8);
    f32x4 w1 = *(const f32x4*)(wp + i * 8 + 4);
#pragma unroll
    for (int t = 0; t < 4; ++t) {
      f32x4 ra = r[2 * t], rb = r[2 * t + 1];
      acc[t] += ra[0] * w0[0] + ra[1] * w0[1] + ra[2] * w0[2] + ra[3] * w0[3]
              + rb[0] * w1[0] + rb[1] * w1[1] + rb[2] * w1[2] + rb[3] * w1[3];
    }
  }
  float sb = srb[c];
#pragma unroll
  for (int t = 0; t < 4; ++t) acc[t] += sb;
  __shared__ float red[4][8];
#pragma unroll
  for (int t = 0; t < 4; ++t) {
    float s = acc[t], q = acc[t] * acc[t];
    for (int m = 32; m; m >>= 1) { s += __shfl_xor(s, m); q += __shfl_xor(q, m); }
    if (lane == 0) { red[t][wv] = s; red[t][4 + wv] = q; }
  }
  __syncthreads();
  float gc = lng[c], bc = lnb[c];
#pragma unroll
  for (int t = 0; t < 4; ++t) {
    float sum = red[t][0] + red[t][1] + red[t][2] + red[t][3];
    float sq  = red[t][4] + red[t][5] + red[t][6] + red[t][7];
    float mu  = sum * (1.f / 256.f);
    float var = sq * (1.f / 256.f) - mu * mu;
    float xn = (acc[t] - mu) * rsqrtf(var + 1e-5f);
    float y = xn * gc + bc;
    float ge = 0.5f * y * (1.f + erff(y * 0.70710678118654752f));
    g[(size_t)(b * 1024 + ty * 32 + txg * 4 + t) * 256 + c] = ge;
  }
}

// ---------------- weight transpose + bf16 cast: Wt[n][k] = bf16(W[k][n]) ----------------
__global__ __launch_bounds__(256) void wtrans_k(const float* __restrict__ W,
                                                short* __restrict__ Wt, int N) {
  int n = blockIdx.x, k = threadIdx.x;
  Wt[(size_t)n * 256 + k] = f2bf(W[(size_t)k * N + n]);
}

// ---------------- GEMM: Y = X[M,256] @ W[256,N]; wave = 16 rows x 128 cols ----------------
// grid: (M/64, N/128). EPI 0: bf16 [row][col] * scale. EPI 1: col<256 -> kbuf bf16; else vT.
// EPI 2: fp32 [row][col] = acc + bias[col].
template <int EPI>
__global__ __launch_bounds__(256) void gemm_k(const float* __restrict__ X,
                                              const short* __restrict__ Wt,
                                              const float* __restrict__ bias,
                                              short* __restrict__ outb,
                                              short* __restrict__ outvT,
                                              float* __restrict__ outf,
                                              int kvshift, float scale) {
  const int lane = threadIdx.x & 63;
  const int wv = threadIdx.x >> 6;
  const int l16 = lane & 15, quad = lane >> 4;
  const int row0 = blockIdx.x * 64 + wv * 16;
  const int col0 = blockIdx.y * 128;
  f32x4 acc[8];
#pragma unroll
  for (int i = 0; i < 8; ++i) { acc[i][0] = 0.f; acc[i][1] = 0.f; acc[i][2] = 0.f; acc[i][3] = 0.f; }
  const float* xrow = X + (size_t)(row0 + l16) * 256 + quad * 8;
  const short* wbase = Wt + (size_t)(col0 + l16) * 256 + quad * 8;
#pragma unroll
  for (int ks = 0; ks < 8; ++ks) {
    f32x4 xa = *(const f32x4*)(xrow + ks * 32);
    f32x4 xb = *(const f32x4*)(xrow + ks * 32 + 4);
    s16x8 a;
    a[0] = f2bf(xa[0]); a[1] = f2bf(xa[1]); a[2] = f2bf(xa[2]); a[3] = f2bf(xa[3]);
    a[4] = f2bf(xb[0]); a[5] = f2bf(xb[1]); a[6] = f2bf(xb[2]); a[7] = f2bf(xb[3]);
#pragma unroll
    for (int nt = 0; nt < 8; ++nt) {
      s16x8 b = *(const s16x8*)(wbase + (size_t)nt * 16 * 256 + ks * 32);
      acc[nt] = mfma16(a, b, acc[nt]);
    }
  }
#pragma unroll
  for (int nt = 0; nt < 8; ++nt) {
#pragma unroll
    for (int r = 0; r < 4; ++r) {
      int col = col0 + nt * 16 + l16;
      int row = row0 + quad * 4 + r;
      float v = acc[nt][r];
      if (EPI == 0) {
        outb[(size_t)row * 256 + col] = f2bf(v * scale);
      } else if (EPI == 1) {
        if (col < 256) {
          outb[(size_t)row * 256 + col] = f2bf(v);
        } else {
          int c2 = col - 256, hh = c2 >> 6, ch = c2 & 63;
          int grp = row >> kvshift, tok = row & ((1 << kvshift) - 1);
          outvT[((size_t)((grp * 4 + hh) * 64 + ch) << kvshift) + tok] = f2bf(v);
        }
      } else {
        outf[(size_t)row * 256 + col] = v + bias[col];
      }
    }
  }
}

// ---------------- flash attention: wave = (window, head), ALL 64 q-rows ----------------
// qt-folded decomposition: each wave processes the full 64x64 q-tile of its
// (win, head). Each K/V tile (16 KB) now feeds 64 MFMA + 4 softmaxes -- 4x the
// arithmetic intensity of the old (win,h,qt) waves and 4x less L2 read traffic
// (the old block's 4 waves loaded byte-identical K/V).
// Tile body is byte-equivalent to the round-3-proven tileStep: pure HIP (no
// inline asm / setprio / sched_barrier -- round 4's NaN implicated those in the
// 4x-unrolled region), single per-wave P region (no parity buffer), XOR-swizzled
// write b64 / read b128 (round-3-proven involution), no block barriers.
// Swapped-operand QK^T (S'=mfma(K,Q)): softmax per-lane (qrow=l16), Q pre-scaled
// by 0.125*log2e so S is in log2 units. T13 defer-rescale (threshold 8).
__global__ __launch_bounds__(256, 2) void attn_k(const short* __restrict__ qbuf,
                                                 const short* __restrict__ kbuf,
                                                 const short* __restrict__ vT,
                                                 float* __restrict__ wf, int kvlen) {
  __shared__ short Plds[4][16 * 64];            // per-wave 16 rows x 128B, XOR-swizzled
  const int w = threadIdx.x >> 6, lane = threadIdx.x & 63;
  const int l16 = lane & 15, quad = lane >> 4;
  const int win = blockIdx.x, h = w;
  const int qrow0 = win * 64;
  const int grp = (kvlen == 64) ? win : (win >= NWF ? 1 : 0);

  s16x8 aq[4][2];
#pragma unroll
  for (int qt = 0; qt < 4; ++qt)
#pragma unroll
    for (int ks = 0; ks < 2; ++ks)
      aq[qt][ks] = *(const s16x8*)(qbuf + (size_t)(qrow0 + qt * 16 + l16) * 256 + h * 64 + ks * 32 + quad * 8);

  f32x4 O[4][4];                                // [qt][nt]
  float m2[4], li[4];
#pragma unroll
  for (int qt = 0; qt < 4; ++qt) {
    m2[qt] = -1e30f; li[qt] = 0.f;
#pragma unroll
    for (int nt = 0; nt < 4; ++nt)
#pragma unroll
      for (int r = 0; r < 4; ++r) O[qt][nt][r] = 0.f;
  }

  const short* kp = kbuf + ((size_t)grp * kvlen + l16) * 256 + h * 64 + quad * 8;
  const short* vp = vT + ((size_t)((grp * 4 + h) * 64) + l16) * kvlen + quad * 8;
  char* Pw = (char*)&Plds[w][0] + l16 * 128;
  const int sw = (l16 & 7) << 4;
  const int ntile = kvlen >> 6;

  for (int t = 0; t < ntile; ++t) {
    // K first (QK waits only on these 8), V second (lands under QK+softmax of qt=0)
    s16x8 kr[2][4];
#pragma unroll
    for (int ks = 0; ks < 2; ++ks)
#pragma unroll
      for (int nt = 0; nt < 4; ++nt)
        kr[ks][nt] = *(const s16x8*)(kp + (size_t)nt * 16 * 256 + ks * 32);
    s16x8 vr[2][4];
#pragma unroll
    for (int ks2 = 0; ks2 < 2; ++ks2)
#pragma unroll
      for (int nt = 0; nt < 4; ++nt)
        vr[ks2][nt] = *(const s16x8*)(vp + (size_t)nt * 16 * kvlen + ks2 * 32);

#pragma unroll
    for (int qt = 0; qt < 4; ++qt) {
      // S'[kpos][qrow]: lane l16 = qrow; kpos = nt*16 + quad*4 + r
      f32x4 S[4];
#pragma unroll
      for (int nt = 0; nt < 4; ++nt)
#pragma unroll
        for (int r = 0; r < 4; ++r) S[nt][r] = 0.f;
#pragma unroll
      for (int ks = 0; ks < 2; ++ks)
#pragma unroll
        for (int nt = 0; nt < 4; ++nt)
          S[nt] = mfma16(kr[ks][nt], aq[qt][ks], S[nt]);
      // row max over the lane's 16 values (compiler fuses to v_max3) + cross-quad
      float mx = S[0][0];
#pragma unroll
      for (int nt = 0; nt < 4; ++nt)
#pragma unroll
        for (int r = 0; r < 4; ++r) mx = fmaxf(mx, S[nt][r]);
      mx = fmaxf(mx, __shfl_xor(mx, 16));
      mx = fmaxf(mx, __shfl_xor(mx, 32));
      if (__any(mx > m2[qt] + 8.0f)) {          // T13: rescale only on real max growth
        float mn = fmaxf(m2[qt], mx);
        float al = __builtin_amdgcn_exp2f(m2[qt] - mn);
        m2[qt] = mn;
        li[qt] *= al;
        float alr[4];
#pragma unroll
        for (int r = 0; r < 4; ++r) alr[r] = __shfl(al, quad * 4 + r);
#pragma unroll
        for (int nt = 0; nt < 4; ++nt)
#pragma unroll
          for (int r = 0; r < 4; ++r) O[qt][nt][r] *= alr[r];
      }
      float rs = 0.f;
#pragma unroll
      for (int nt = 0; nt < 4; ++nt)
#pragma unroll
        for (int r = 0; r < 4; ++r) {
          float p = __builtin_amdgcn_exp2f(S[nt][r] - m2[qt]);
          S[nt][r] = p;
          rs += p;
        }
      li[qt] += rs;                             // cross-quad sum deferred to epilogue
      // P -> bf16 packed -> swizzled per-wave LDS (no barriers, single region:
      // write b64 then read b128 of the same rows, round-3-proven ordering)
#pragma unroll
      for (int nt = 0; nt < 4; ++nt) {
        uint2 pw;
        pw.x = pk2bf(S[nt][0], S[nt][1]);
        pw.y = pk2bf(S[nt][2], S[nt][3]);
        *(uint2*)(Pw + ((nt * 32 + quad * 8) ^ sw)) = pw;
      }
#pragma unroll
      for (int ks2 = 0; ks2 < 2; ++ks2) {
        s16x8 ap = *(const s16x8*)(Pw + ((ks2 * 64 + quad * 16) ^ sw));
#pragma unroll
        for (int nt = 0; nt < 4; ++nt)
          O[qt][nt] = mfma16(ap, vr[ks2][nt], O[qt][nt]);
      }
    }
    kp += 64 * 256;
    vp += 64;
  }

#pragma unroll
  for (int qt = 0; qt < 4; ++qt) {
    float l = li[qt];
    l += __shfl_xor(l, 16);
    l += __shfl_xor(l, 32);
    float inv = 1.f / l;
    float invr[4];
#pragma unroll
    for (int r = 0; r < 4; ++r) invr[r] = __shfl(inv, quad * 4 + r);
#pragma unroll
    for (int nt = 0; nt < 4; ++nt)
#pragma unroll
      for (int r = 0; r < 4; ++r) {
        size_t oi = (size_t)(qrow0 + qt * 16 + quad * 4 + r) * 256 + h * 64 + nt * 16 + l16;
        wf[oi] += O[qt][nt][r] * invr[r];
      }
  }
}

// ---------------- scatter-add projected windows into out (LDS transpose) ----------------
__global__ __launch_bounds__(256) void scatter_k(const float* __restrict__ proj,
                                                 const int* __restrict__ selidx,
                                                 float* __restrict__ out) {
  __shared__ float tile[64][33];
  int slot = blockIdx.x;
  int b = slot >= NWF;
  int w = selidx[slot];
  int y0 = (w >> 5) * 8, x0 = (w & 31) * 8;
  int tid = threadIdx.x;
  int cc2 = tid & 31, t4 = tid >> 5;                    // coalesced proj read
  int j = tid & 7, i = (tid >> 3) & 7, c4 = tid >> 6;   // out RMW mapping
  for (int c0 = 0; c0 < 256; c0 += 32) {
    for (int ts = 0; ts < 8; ++ts) {
      int tok = ts * 8 + t4;
      tile[tok][cc2] = proj[(size_t)(slot * 64 + tok) * 256 + c0 + cc2];
    }
    __syncthreads();
    for (int cs = 0; cs < 8; ++cs) {
      int c = c0 + cs * 4 + c4;
      size_t oidx = ((size_t)(b * 256 + c) * 256 + y0 + i) * 256 + x0 + j;
      out[oidx] += tile[i * 8 + j][cs * 4 + c4];
    }
    __syncthreads();
  }
}

extern "C" void kernel_launch(void* const* d_in, const int* in_sizes, int n_in,
                              void* d_out, int out_size, void* d_ws, size_t ws_size,
                              hipStream_t stream) {
  const float* fm    = (const float*)d_in[0];
  const float* unc   = (const float*)d_in[1];
  const float* srw   = (const float*)d_in[2];
  const float* srb   = (const float*)d_in[3];
  const float* lng   = (const float*)d_in[4];
  const float* lnb   = (const float*)d_in[5];
  const float* wq_l  = (const float*)d_in[6];
  const float* wkv_l = (const float*)d_in[7];
  const float* wq_g  = (const float*)d_in[8];
  const float* wkv_g = (const float*)d_in[9];
  const float* wpm   = (const float*)d_in[10];
  const float* bp    = (const float*)d_in[11];
  float* out = (float*)d_out;

  char* ws = (char*)d_ws;
  size_t off = 0;
  auto alloc = [&](size_t bytes) -> char* {
    char* p = ws + off;
    off += (bytes + 255) & ~(size_t)255;
    return p;
  };
  float* wf     = (float*)alloc((size_t)MROWS * 256 * 4);
  short* qbuf   = (short*)alloc((size_t)MROWS * 256 * 2);
  short* kbufl  = (short*)alloc((size_t)MROWS * 256 * 2);   // contiguous with qbuf
  short* vTl    = (short*)alloc((size_t)MROWS * 256 * 2);
  short* kbufg  = (short*)alloc((size_t)2048 * 256 * 2);
  short* vTg    = (short*)alloc((size_t)2048 * 256 * 2);
  float* g      = (float*)alloc((size_t)2048 * 256 * 4);
  float* scores = (float*)alloc(2048 * 4);
  int*   selidx = (int*)alloc(NWTOT * 4);
  short* wtql   = (short*)alloc(256 * 256 * 2);
  short* wtkvl  = (short*)alloc(512 * 256 * 2);
  short* wtqg   = (short*)alloc(256 * 256 * 2);
  short* wtkvg  = (short*)alloc(512 * 256 * 2);
  short* wtp    = (short*)alloc(256 * 256 * 2);
  float* proj   = (float*)qbuf;   // aliases qbuf+kbufl (both dead by projection time)

  const float C1 = 0.125f * 1.4426950408889634f;   // head-scale * log2(e)

  // weights -> bf16 transposed
  wtrans_k<<<256, 256, 0, stream>>>(wq_l, wtql, 256);
  wtrans_k<<<512, 256, 0, stream>>>(wkv_l, wtkvl, 512);
  wtrans_k<<<256, 256, 0, stream>>>(wq_g, wtqg, 256);
  wtrans_k<<<512, 256, 0, stream>>>(wkv_g, wtkvg, 512);
  wtrans_k<<<256, 256, 0, stream>>>(wpm, wtp, 256);

  // selection
  score_k<<<2048, 64, 0, stream>>>(unc, scores);
  topk_k<<<2, 1024, 0, stream>>>(scores, selidx);
  gather_k<<<NWTOT, 256, 0, stream>>>(fm, selidx, wf);

  // fused identity-copy + global branch (conv + LN + GELU)
  convcopy_k<<<512, 256, 0, stream>>>(fm, srw, srb, lng, lnb, g, out);

  // local window attention (q pre-scaled so S is in log2 units)
  gemm_k<0><<<dim3(NWTOT, 2), 256, 0, stream>>>(wf, wtql, nullptr, qbuf, nullptr, nullptr, 0, C1);
  gemm_k<1><<<dim3(NWTOT, 4), 256, 0, stream>>>(wf, wtkvl, nullptr, kbufl, vTl, nullptr, 6, 1.0f);
  attn_k<<<NWTOT, 256, 0, stream>>>(qbuf, kbufl, vTl, wf, 64);

  // global cross attention
  gemm_k<0><<<dim3(NWTOT, 2), 256, 0, stream>>>(wf, wtqg, nullptr, qbuf, nullptr, nullptr, 0, C1);
  gemm_k<1><<<dim3(32, 4), 256, 0, stream>>>(g, wtkvg, nullptr, kbufg, vTg, nullptr, 10, 1.0f);
  attn_k<<<NWTOT, 256, 0, stream>>>(qbuf, kbufg, vTg, wf, 1024);

  // projection + scatter-add
  gemm_k<2><<<dim3(NWTOT, 2), 256, 0, stream>>>(wf, wtp, bp, nullptr, nullptr, proj, 0, 1.0f);
  scatter_k<<<NWTOT, 256, 0, stream>>>(proj, selidx, out);
}

// Round 6
// 827.214 us; speedup vs baseline: 1.3495x; 1.1239x over previous
//
#include <hip/hip_runtime.h>
#include <math.h>

#define NWF    307
#define NWTOT  614
#define MROWS  39296   // NWTOT * 64

typedef float f32x4 __attribute__((ext_vector_type(4)));
typedef short s16x8 __attribute__((ext_vector_type(8)));

__device__ __forceinline__ short f2bf(float f) {
  unsigned int u = __builtin_bit_cast(unsigned int, f);
  u += 0x7fffu + ((u >> 16) & 1u);
  return (short)(u >> 16);
}

__device__ __forceinline__ unsigned int pk2bf(float lo, float hi) {
  return (unsigned int)(unsigned short)f2bf(lo) |
         ((unsigned int)(unsigned short)f2bf(hi) << 16);
}

__device__ __forceinline__ f32x4 mfma16(s16x8 a, s16x8 b, f32x4 c) {
  return __builtin_amdgcn_mfma_f32_16x16x32_bf16(a, b, c, 0, 0, 0);
}

// ---------------- window scores: mean of 64 uncertainty values ----------------
__global__ __launch_bounds__(64) void score_k(const float* __restrict__ unc,
                                              float* __restrict__ scores) {
  int blk = blockIdx.x;              // 0..2047 = b*1024 + win
  int b = blk >> 10, t = blk & 1023;
  int ty = t >> 5, tx = t & 31;
  int lane = threadIdx.x;
  float v = unc[(size_t)b * 65536 + (size_t)(ty * 8 + (lane >> 3)) * 256 + tx * 8 + (lane & 7)];
  for (int m = 32; m; m >>= 1) v += __shfl_xor(v, m);
  if (lane == 0) scores[blk] = v * (1.0f / 64.0f);
}

// ---------------- exact top-k via rank counting (per batch) ----------------
__global__ __launch_bounds__(1024) void topk_k(const float* __restrict__ scores,
                                               int* __restrict__ selidx) {
  __shared__ float sc[1024];
  int b = blockIdx.x, t = threadIdx.x;
  float s = scores[b * 1024 + t];
  sc[t] = s;
  __syncthreads();
  int rank = 0;
  for (int j = 0; j < 1024; ++j) {
    float o = sc[j];
    rank += (o > s) || (o == s && j < t);
  }
  if (rank < NWF) selidx[b * NWF + rank] = t;
}

// ---------------- gather selected windows: wf[slot][tok][c] ----------------
__global__ __launch_bounds__(256) void gather_k(const float* __restrict__ fm,
                                                const int* __restrict__ selidx,
                                                float* __restrict__ wf) {
  __shared__ float tile[64][33];
  int slot = blockIdx.x;
  int b = slot >= NWF;
  int w = selidx[slot];
  int y0 = (w >> 5) * 8, x0 = (w & 31) * 8;
  int tid = threadIdx.x;
  int j = tid & 7, i = (tid >> 3) & 7, c4 = tid >> 6;   // read mapping
  int cc2 = tid & 31, t4 = tid >> 5;                    // write mapping
  for (int c0 = 0; c0 < 256; c0 += 32) {
    for (int cs = 0; cs < 8; ++cs) {
      int c = c0 + cs * 4 + c4;
      tile[i * 8 + j][cs * 4 + c4] =
          fm[((size_t)(b * 256 + c) * 256 + y0 + i) * 256 + x0 + j];
    }
    __syncthreads();
    for (int ts = 0; ts < 8; ++ts) {
      int tok = ts * 8 + t4;
      wf[(size_t)(slot * 64 + tok) * 256 + c0 + cc2] = tile[tok][cc2];
    }
    __syncthreads();
  }
}

// ------- phase A: coalesced fm->out copy + depthwise 8x8/8 conv partials -------
// grid: 16384 = b(2) * ty(32) * c(256); block 256 = 4 waves.
// Wave w owns image rows {ty*8+w, ty*8+w+4}, lanes along x (f32x4 each):
// perfectly coalesced 1KB/wave loads+stores (the old layout put 64 lanes at
// 256KB stride -> 64 scattered 16B transactions, 9% occupancy, 2.75 TB/s).
// Conv: lane partial = dot4(fm4, w4); shfl_xor(1) joins the two j-halves of a
// token; LDS joins the 4 waves (8 rows). Pre-LN result -> g0[token][c].
__global__ __launch_bounds__(256) void convcopy_k(const float* __restrict__ fm,
                                                  const float* __restrict__ srw,
                                                  const float* __restrict__ srb,
                                                  float* __restrict__ g0,
                                                  float* __restrict__ out) {
  int blk = blockIdx.x;              // b*8192 + ty*256 + c
  int c = blk & 255, ty = (blk >> 8) & 31, b = blk >> 13;
  int t = threadIdx.x;
  int w = t >> 6, l = t & 63;
  size_t base = ((size_t)(b * 256 + c) * 256 + ty * 8) * 256;
  const float* wp = srw + c * 64;
  int j0 = (l & 1) * 4;
  float acc = 0.f;
#pragma unroll
  for (int it = 0; it < 2; ++it) {
    int row = it * 4 + w;
    size_t off = base + (size_t)row * 256 + l * 4;
    f32x4 v = *(const f32x4*)(fm + off);
    *(f32x4*)(out + off) = v;
    f32x4 wv = *(const f32x4*)(wp + row * 8 + j0);
    acc += v[0] * wv[0] + v[1] * wv[1] + v[2] * wv[2] + v[3] * wv[3];
  }
  acc += __shfl_xor(acc, 1);         // join the two 4-wide j-halves of token l>>1
  __shared__ float red[32][5];
  if ((l & 1) == 0) red[l >> 1][w] = acc;
  __syncthreads();
  if (t < 32) {
    float s = red[t][0] + red[t][1] + red[t][2] + red[t][3] + srb[c];
    g0[(size_t)(b * 1024 + ty * 32 + t) * 256 + c] = s;
  }
}

// ------- phase B: LayerNorm + exact GELU over g0 -> g (2048 tokens x 256 ch) -------
__global__ __launch_bounds__(256) void lnact_k(const float* __restrict__ g0,
                                               const float* __restrict__ lng,
                                               const float* __restrict__ lnb,
                                               float* __restrict__ g) {
  int tok4 = blockIdx.x;             // 512 blocks, 4 tokens each
  int c = threadIdx.x;
  int lane = c & 63, wv = c >> 6;
  float x[4];
#pragma unroll
  for (int t = 0; t < 4; ++t) x[t] = g0[(size_t)(tok4 * 4 + t) * 256 + c];
  __shared__ float red[4][8];
#pragma unroll
  for (int t = 0; t < 4; ++t) {
    float s = x[t], q = x[t] * x[t];
    for (int m = 32; m; m >>= 1) { s += __shfl_xor(s, m); q += __shfl_xor(q, m); }
    if (lane == 0) { red[t][wv] = s; red[t][4 + wv] = q; }
  }
  __syncthreads();
  float gc = lng[c], bc = lnb[c];
#pragma unroll
  for (int t = 0; t < 4; ++t) {
    float sum = red[t][0] + red[t][1] + red[t][2] + red[t][3];
    float sq  = red[t][4] + red[t][5] + red[t][6] + red[t][7];
    float mu  = sum * (1.f / 256.f);
    float var = sq * (1.f / 256.f) - mu * mu;
    float xn = (x[t] - mu) * rsqrtf(var + 1e-5f);
    float y = xn * gc + bc;
    g[(size_t)(tok4 * 4 + t) * 256 + c] = 0.5f * y * (1.f + erff(y * 0.70710678118654752f));
  }
}

// ---------------- weight transpose + bf16 cast: Wt[n][k] = bf16(W[k][n]) ----------------
__global__ __launch_bounds__(256) void wtrans_k(const float* __restrict__ W,
                                                short* __restrict__ Wt, int N) {
  int n = blockIdx.x, k = threadIdx.x;
  Wt[(size_t)n * 256 + k] = f2bf(W[(size_t)k * N + n]);
}

// ---------------- GEMM: Y = X[M,256] @ W[256,N]; wave = 16 rows x 128 cols ----------------
// grid: (M/64, N/128). EPI 0: bf16 [row][col] * scale. EPI 1: col<256 -> kbuf bf16; else vT.
// EPI 2: fp32 [row][col] = acc + bias[col].
template <int EPI>
__global__ __launch_bounds__(256) void gemm_k(const float* __restrict__ X,
                                              const short* __restrict__ Wt,
                                              const float* __restrict__ bias,
                                              short* __restrict__ outb,
                                              short* __restrict__ outvT,
                                              float* __restrict__ outf,
                                              int kvshift, float scale) {
  const int lane = threadIdx.x & 63;
  const int wv = threadIdx.x >> 6;
  const int l16 = lane & 15, quad = lane >> 4;
  const int row0 = blockIdx.x * 64 + wv * 16;
  const int col0 = blockIdx.y * 128;
  f32x4 acc[8];
#pragma unroll
  for (int i = 0; i < 8; ++i) { acc[i][0] = 0.f; acc[i][1] = 0.f; acc[i][2] = 0.f; acc[i][3] = 0.f; }
  const float* xrow = X + (size_t)(row0 + l16) * 256 + quad * 8;
  const short* wbase = Wt + (size_t)(col0 + l16) * 256 + quad * 8;
#pragma unroll
  for (int ks = 0; ks < 8; ++ks) {
    f32x4 xa = *(const f32x4*)(xrow + ks * 32);
    f32x4 xb = *(const f32x4*)(xrow + ks * 32 + 4);
    s16x8 a;
    a[0] = f2bf(xa[0]); a[1] = f2bf(xa[1]); a[2] = f2bf(xa[2]); a[3] = f2bf(xa[3]);
    a[4] = f2bf(xb[0]); a[5] = f2bf(xb[1]); a[6] = f2bf(xb[2]); a[7] = f2bf(xb[3]);
#pragma unroll
    for (int nt = 0; nt < 8; ++nt) {
      s16x8 b = *(const s16x8*)(wbase + (size_t)nt * 16 * 256 + ks * 32);
      acc[nt] = mfma16(a, b, acc[nt]);
    }
  }
#pragma unroll
  for (int nt = 0; nt < 8; ++nt) {
#pragma unroll
    for (int r = 0; r < 4; ++r) {
      int col = col0 + nt * 16 + l16;
      int row = row0 + quad * 4 + r;
      float v = acc[nt][r];
      if (EPI == 0) {
        outb[(size_t)row * 256 + col] = f2bf(v * scale);
      } else if (EPI == 1) {
        if (col < 256) {
          outb[(size_t)row * 256 + col] = f2bf(v);
        } else {
          int c2 = col - 256, hh = c2 >> 6, ch = c2 & 63;
          int grp = row >> kvshift, tok = row & ((1 << kvshift) - 1);
          outvT[((size_t)((grp * 4 + hh) * 64 + ch) << kvshift) + tok] = f2bf(v);
        }
      } else {
        outf[(size_t)row * 256 + col] = v + bias[col];
      }
    }
  }
}

// ---------------- flash attention: wave = (window, head), ALL 64 q-rows ----------------
// qt-folded decomposition (round-5 proven): each wave processes the full 64x64
// q-tile of its (win, head); each K/V tile (16 KB) feeds 64 MFMA + 4 softmaxes.
// Pure HIP tile body; single per-wave XOR-swizzled P region; no block barriers.
// Swapped-operand QK^T (S'=mfma(K,Q)): softmax per-lane (qrow=l16), Q pre-scaled
// by 0.125*log2e so S is in log2 units. T13 defer-rescale (threshold 8).
__global__ __launch_bounds__(256, 2) void attn_k(const short* __restrict__ qbuf,
                                                 const short* __restrict__ kbuf,
                                                 const short* __restrict__ vT,
                                                 float* __restrict__ wf, int kvlen) {
  __shared__ short Plds[4][16 * 64];            // per-wave 16 rows x 128B, XOR-swizzled
  const int w = threadIdx.x >> 6, lane = threadIdx.x & 63;
  const int l16 = lane & 15, quad = lane >> 4;
  const int win = blockIdx.x, h = w;
  const int qrow0 = win * 64;
  const int grp = (kvlen == 64) ? win : (win >= NWF ? 1 : 0);

  s16x8 aq[4][2];
#pragma unroll
  for (int qt = 0; qt < 4; ++qt)
#pragma unroll
    for (int ks = 0; ks < 2; ++ks)
      aq[qt][ks] = *(const s16x8*)(qbuf + (size_t)(qrow0 + qt * 16 + l16) * 256 + h * 64 + ks * 32 + quad * 8);

  f32x4 O[4][4];                                // [qt][nt]
  float m2[4], li[4];
#pragma unroll
  for (int qt = 0; qt < 4; ++qt) {
    m2[qt] = -1e30f; li[qt] = 0.f;
#pragma unroll
    for (int nt = 0; nt < 4; ++nt)
#pragma unroll
      for (int r = 0; r < 4; ++r) O[qt][nt][r] = 0.f;
  }

  const short* kp = kbuf + ((size_t)grp * kvlen + l16) * 256 + h * 64 + quad * 8;
  const short* vp = vT + ((size_t)((grp * 4 + h) * 64) + l16) * kvlen + quad * 8;
  char* Pw = (char*)&Plds[w][0] + l16 * 128;
  const int sw = (l16 & 7) << 4;
  const int ntile = kvlen >> 6;

  for (int t = 0; t < ntile; ++t) {
    // K first (QK waits only on these 8), V second (lands under QK+softmax of qt=0)
    s16x8 kr[2][4];
#pragma unroll
    for (int ks = 0; ks < 2; ++ks)
#pragma unroll
      for (int nt = 0; nt < 4; ++nt)
        kr[ks][nt] = *(const s16x8*)(kp + (size_t)nt * 16 * 256 + ks * 32);
    s16x8 vr[2][4];
#pragma unroll
    for (int ks2 = 0; ks2 < 2; ++ks2)
#pragma unroll
      for (int nt = 0; nt < 4; ++nt)
        vr[ks2][nt] = *(const s16x8*)(vp + (size_t)nt * 16 * kvlen + ks2 * 32);

#pragma unroll
    for (int qt = 0; qt < 4; ++qt) {
      // S'[kpos][qrow]: lane l16 = qrow; kpos = nt*16 + quad*4 + r
      f32x4 S[4];
#pragma unroll
      for (int nt = 0; nt < 4; ++nt)
#pragma unroll
        for (int r = 0; r < 4; ++r) S[nt][r] = 0.f;
#pragma unroll
      for (int ks = 0; ks < 2; ++ks)
#pragma unroll
        for (int nt = 0; nt < 4; ++nt)
          S[nt] = mfma16(kr[ks][nt], aq[qt][ks], S[nt]);
      // row max over the lane's 16 values (compiler fuses to v_max3) + cross-quad
      float mx = S[0][0];
#pragma unroll
      for (int nt = 0; nt < 4; ++nt)
#pragma unroll
        for (int r = 0; r < 4; ++r) mx = fmaxf(mx, S[nt][r]);
      mx = fmaxf(mx, __shfl_xor(mx, 16));
      mx = fmaxf(mx, __shfl_xor(mx, 32));
      if (__any(mx > m2[qt] + 8.0f)) {          // T13: rescale only on real max growth
        float mn = fmaxf(m2[qt], mx);
        float al = __builtin_amdgcn_exp2f(m2[qt] - mn);
        m2[qt] = mn;
        li[qt] *= al;
        float alr[4];
#pragma unroll
        for (int r = 0; r < 4; ++r) alr[r] = __shfl(al, quad * 4 + r);
#pragma unroll
        for (int nt = 0; nt < 4; ++nt)
#pragma unroll
          for (int r = 0; r < 4; ++r) O[qt][nt][r] *= alr[r];
      }
      float rs = 0.f;
#pragma unroll
      for (int nt = 0; nt < 4; ++nt)
#pragma unroll
        for (int r = 0; r < 4; ++r) {
          float p = __builtin_amdgcn_exp2f(S[nt][r] - m2[qt]);
          S[nt][r] = p;
          rs += p;
        }
      li[qt] += rs;                             // cross-quad sum deferred to epilogue
      // P -> bf16 packed -> swizzled per-wave LDS (no barriers, single region:
      // write b64 then read b128 of the same rows, proven ordering)
#pragma unroll
      for (int nt = 0; nt < 4; ++nt) {
        uint2 pw;
        pw.x = pk2bf(S[nt][0], S[nt][1]);
        pw.y = pk2bf(S[nt][2], S[nt][3]);
        *(uint2*)(Pw + ((nt * 32 + quad * 8) ^ sw)) = pw;
      }
#pragma unroll
      for (int ks2 = 0; ks2 < 2; ++ks2) {
        s16x8 ap = *(const s16x8*)(Pw + ((ks2 * 64 + quad * 16) ^ sw));
#pragma unroll
        for (int nt = 0; nt < 4; ++nt)
          O[qt][nt] = mfma16(ap, vr[ks2][nt], O[qt][nt]);
      }
    }
    kp += 64 * 256;
    vp += 64;
  }

#pragma unroll
  for (int qt = 0; qt < 4; ++qt) {
    float l = li[qt];
    l += __shfl_xor(l, 16);
    l += __shfl_xor(l, 32);
    float inv = 1.f / l;
    float invr[4];
#pragma unroll
    for (int r = 0; r < 4; ++r) invr[r] = __shfl(inv, quad * 4 + r);
#pragma unroll
    for (int nt = 0; nt < 4; ++nt)
#pragma unroll
      for (int r = 0; r < 4; ++r) {
        size_t oi = (size_t)(qrow0 + qt * 16 + quad * 4 + r) * 256 + h * 64 + nt * 16 + l16;
        wf[oi] += O[qt][nt][r] * invr[r];
      }
  }
}

// ---------------- scatter-add projected windows into out (LDS transpose) ----------------
__global__ __launch_bounds__(256) void scatter_k(const float* __restrict__ proj,
                                                 const int* __restrict__ selidx,
                                                 float* __restrict__ out) {
  __shared__ float tile[64][33];
  int slot = blockIdx.x;
  int b = slot >= NWF;
  int w = selidx[slot];
  int y0 = (w >> 5) * 8, x0 = (w & 31) * 8;
  int tid = threadIdx.x;
  int cc2 = tid & 31, t4 = tid >> 5;                    // coalesced proj read
  int j = tid & 7, i = (tid >> 3) & 7, c4 = tid >> 6;   // out RMW mapping
  for (int c0 = 0; c0 < 256; c0 += 32) {
    for (int ts = 0; ts < 8; ++ts) {
      int tok = ts * 8 + t4;
      tile[tok][cc2] = proj[(size_t)(slot * 64 + tok) * 256 + c0 + cc2];
    }
    __syncthreads();
    for (int cs = 0; cs < 8; ++cs) {
      int c = c0 + cs * 4 + c4;
      size_t oidx = ((size_t)(b * 256 + c) * 256 + y0 + i) * 256 + x0 + j;
      out[oidx] += tile[i * 8 + j][cs * 4 + c4];
    }
    __syncthreads();
  }
}

extern "C" void kernel_launch(void* const* d_in, const int* in_sizes, int n_in,
                              void* d_out, int out_size, void* d_ws, size_t ws_size,
                              hipStream_t stream) {
  const float* fm    = (const float*)d_in[0];
  const float* unc   = (const float*)d_in[1];
  const float* srw   = (const float*)d_in[2];
  const float* srb   = (const float*)d_in[3];
  const float* lng   = (const float*)d_in[4];
  const float* lnb   = (const float*)d_in[5];
  const float* wq_l  = (const float*)d_in[6];
  const float* wkv_l = (const float*)d_in[7];
  const float* wq_g  = (const float*)d_in[8];
  const float* wkv_g = (const float*)d_in[9];
  const float* wpm   = (const float*)d_in[10];
  const float* bp    = (const float*)d_in[11];
  float* out = (float*)d_out;

  char* ws = (char*)d_ws;
  size_t off = 0;
  auto alloc = [&](size_t bytes) -> char* {
    char* p = ws + off;
    off += (bytes + 255) & ~(size_t)255;
    return p;
  };
  float* wf     = (float*)alloc((size_t)MROWS * 256 * 4);
  short* qbuf   = (short*)alloc((size_t)MROWS * 256 * 2);
  short* kbufl  = (short*)alloc((size_t)MROWS * 256 * 2);   // contiguous with qbuf
  short* vTl    = (short*)alloc((size_t)MROWS * 256 * 2);
  short* kbufg  = (short*)alloc((size_t)2048 * 256 * 2);
  short* vTg    = (short*)alloc((size_t)2048 * 256 * 2);
  float* g      = (float*)alloc((size_t)2048 * 256 * 4);
  float* g0     = (float*)alloc((size_t)2048 * 256 * 4);
  float* scores = (float*)alloc(2048 * 4);
  int*   selidx = (int*)alloc(NWTOT * 4);
  short* wtql   = (short*)alloc(256 * 256 * 2);
  short* wtkvl  = (short*)alloc(512 * 256 * 2);
  short* wtqg   = (short*)alloc(256 * 256 * 2);
  short* wtkvg  = (short*)alloc(512 * 256 * 2);
  short* wtp    = (short*)alloc(256 * 256 * 2);
  float* proj   = (float*)qbuf;   // aliases qbuf+kbufl (both dead by projection time)

  const float C1 = 0.125f * 1.4426950408889634f;   // head-scale * log2(e)

  // weights -> bf16 transposed
  wtrans_k<<<256, 256, 0, stream>>>(wq_l, wtql, 256);
  wtrans_k<<<512, 256, 0, stream>>>(wkv_l, wtkvl, 512);
  wtrans_k<<<256, 256, 0, stream>>>(wq_g, wtqg, 256);
  wtrans_k<<<512, 256, 0, stream>>>(wkv_g, wtkvg, 512);
  wtrans_k<<<256, 256, 0, stream>>>(wpm, wtp, 256);

  // selection
  score_k<<<2048, 64, 0, stream>>>(unc, scores);
  topk_k<<<2, 1024, 0, stream>>>(scores, selidx);
  gather_k<<<NWTOT, 256, 0, stream>>>(fm, selidx, wf);

  // global branch: coalesced copy + conv partials, then LN+GELU
  convcopy_k<<<16384, 256, 0, stream>>>(fm, srw, srb, g0, out);
  lnact_k<<<512, 256, 0, stream>>>(g0, lng, lnb, g);

  // local window attention (q pre-scaled so S is in log2 units)
  gemm_k<0><<<dim3(NWTOT, 2), 256, 0, stream>>>(wf, wtql, nullptr, qbuf, nullptr, nullptr, 0, C1);
  gemm_k<1><<<dim3(NWTOT, 4), 256, 0, stream>>>(wf, wtkvl, nullptr, kbufl, vTl, nullptr, 6, 1.0f);
  attn_k<<<NWTOT, 256, 0, stream>>>(qbuf, kbufl, vTl, wf, 64);

  // global cross attention
  gemm_k<0><<<dim3(NWTOT, 2), 256, 0, stream>>>(wf, wtqg, nullptr, qbuf, nullptr, nullptr, 0, C1);
  gemm_k<1><<<dim3(32, 4), 256, 0, stream>>>(g, wtkvg, nullptr, kbufg, vTg, nullptr, 10, 1.0f);
  attn_k<<<NWTOT, 256, 0, stream>>>(qbuf, kbufg, vTg, wf, 1024);

  // projection + scatter-add
  gemm_k<2><<<dim3(NWTOT, 2), 256, 0, stream>>>(wf, wtp, bp, nullptr, nullptr, proj, 0, 1.0f);
  scatter_k<<<NWTOT, 256, 0, stream>>>(proj, selidx, out);
}